// Round 17
// baseline (471.569 us; speedup 1.0000x reference)
//
#include <hip/hip_runtime.h>

typedef unsigned short u16;
typedef unsigned int u32;
typedef __attribute__((ext_vector_type(4))) float f32x4;
typedef __attribute__((ext_vector_type(16))) float f32x16;
typedef __attribute__((ext_vector_type(8))) short bf16x8;
typedef __attribute__((ext_vector_type(2))) unsigned int u32x2;

#define S_LEN 2048
#define NHEAD 32
#define HDD 128
#define HID 4096
#define N_QKV 12288
#define KDIM 4096
#define RS 12288  // mixed row stride (elements)

__device__ __forceinline__ u16 f2bf(float f) {
  u32 u = __builtin_bit_cast(u32, f);
  u = (u + 0x7FFFu + ((u >> 16) & 1u)) >> 16;
  return (u16)u;
}
__device__ __forceinline__ float bf2f(u16 h) {
  u32 u = ((u32)h) << 16;
  return __builtin_bit_cast(float, u);
}

// Gray-key slot swizzle (R13-verified: 0 bank conflicts with 32x32 frags)
__device__ __forceinline__ int gkey(int line) { return (line ^ (line >> 1)) & 7; }

__device__ __forceinline__ void gl2lds16(const void* g, void* l) {
  __builtin_amdgcn_global_load_lds(
      (const __attribute__((address_space(1))) u32*)g,
      (__attribute__((address_space(3))) u32*)l, 16, 0, 0);
}

#define FULL_BAR()                          \
  {                                         \
    asm volatile("" ::: "memory");          \
    __builtin_amdgcn_s_barrier();           \
    asm volatile("" ::: "memory");          \
  }

// ------ fused fp32 -> bf16 conversion (W1, X) + RoPE trig tables ----------
__global__ __launch_bounds__(256) void cvt3_kernel(const float* __restrict__ s0, u16* __restrict__ d0, int n0,
                                                   const float* __restrict__ s2, u16* __restrict__ d2, int n2,
                                                   float* __restrict__ cos_t, float* __restrict__ sin_t) {
  int i = blockIdx.x * blockDim.x + threadIdx.x;
  if (i < S_LEN * 32) {
    int s = i >> 5, ii = i & 31;
    float invf = expf(-0.28782313662425572f * (float)ii);
    float a = (float)s * invf;
    cos_t[i] = cosf(a);
    sin_t[i] = sinf(a);
  }
  int st = gridDim.x * blockDim.x;
  int ntot = n0 + n2;
  for (; i < ntot; i += st) {
    const float* s;
    u16* d;
    int j = i;
    if (j < n0) {
      s = s0; d = d0;
    } else {
      j -= n0; s = s2; d = d2;
    }
    float4 v = ((const float4*)s)[j];
    u32x2 o;
    o.x = (u32)f2bf(v.x) | ((u32)f2bf(v.y) << 16);
    o.y = (u32)f2bf(v.z) | ((u32)f2bf(v.w) << 16);
    ((u32x2*)d)[j] = o;
  }
}

// -------- QKV GEMM: 256x384, BK=32, ring-3, 32x32x16, Gray-key ------------
// K-ROPE FUSED IN EPILOGUE: block = one head (BN=384). Wave 1 holds K-half0
// pairs (i,i+32) as (ni=1,ni=2) lane-locally (l31=i, pos=pid[row]); wave 2
// holds K-half1 pairs as (ni=0,ni=1) (pos=pid[S_LEN+row]). Rope applied on
// f32 acc+bias before the single bf16 rounding. ropek kernel eliminated.
__global__ __launch_bounds__(512, 2) void gemmQ(const u16* __restrict__ A,
                                                const u16* __restrict__ B,
                                                const float* __restrict__ bias,
                                                const int* __restrict__ pid,
                                                const float* __restrict__ cos_t,
                                                const float* __restrict__ sin_t,
                                                u16* __restrict__ outb) {
  __shared__ __align__(16) char lds[3][40960];

  const int tid = threadIdx.x;
  const int lane = tid & 63, w = tid >> 6;
  const int l31 = lane & 31, hh = lane >> 5;
  const int wm = w >> 2, wn = w & 3;  // 2M x 4N

  int x = blockIdx.x & 7, loc = blockIdx.x >> 3;
  int mb = loc & 7, nb = x * 4 + (loc >> 3);
  const int bm = mb * 256, bn = nb * 384;

  f32x16 acc[4][3];
#pragma unroll
  for (int mi = 0; mi < 4; ++mi)
#pragma unroll
    for (int ni = 0; ni < 3; ++ni)
#pragma unroll
      for (int r = 0; r < 16; ++r) acc[mi][ni][r] = 0.f;

  const size_t K2 = (size_t)KDIM * 2;

  const char* gA[2];
#pragma unroll
  for (int j = 0; j < 2; ++j) {
    int slot = j * 512 + tid;
    int line = slot >> 3;
    int sl = (slot & 7) ^ gkey(line);
    int row = 2 * line + (sl >> 2);
    int colb = (sl & 3) * 16;
    gA[j] = (const char*)A + (size_t)(bm + row) * K2 + colb;
  }
  const char* gB[3];
#pragma unroll
  for (int j = 0; j < 3; ++j) {
    int slot = j * 512 + tid;
    int line = slot >> 3;
    int sl = (slot & 7) ^ gkey(line);
    int row = 2 * line + (sl >> 2);
    int colb = (sl & 3) * 16;
    gB[j] = (const char*)B + (size_t)(bn + row) * K2 + colb;
  }
  const int ldst = w * 1024;

#define QIA(t, bi)                                                  \
  {                                                                 \
    char* Lb = lds[bi];                                             \
    gl2lds16(gA[0] + (size_t)(t) * 64, Lb + ldst);                  \
    gl2lds16(gA[1] + (size_t)(t) * 64, Lb + 8192 + ldst);           \
  }
#define QIB(t, bi)                                                  \
  {                                                                 \
    char* Lb = lds[bi] + 16384;                                     \
    _Pragma("unroll")                                               \
    for (int j = 0; j < 3; ++j)                                     \
      gl2lds16(gB[j] + (size_t)(t) * 64, Lb + j * 8192 + ldst);     \
  }

  int offA[4][2], offB[3][2];
#pragma unroll
  for (int mi = 0; mi < 4; ++mi) {
    int r = wm * 128 + mi * 32 + l31;
    int line = r >> 1;
#pragma unroll
    for (int kk = 0; kk < 2; ++kk) {
      int sl = (((r & 1) << 2) + kk * 2 + hh) ^ gkey(line);
      offA[mi][kk] = line * 128 + sl * 16;
    }
  }
#pragma unroll
  for (int ni = 0; ni < 3; ++ni) {
    int r = wn * 96 + ni * 32 + l31;
    int line = r >> 1;
#pragma unroll
    for (int kk = 0; kk < 2; ++kk) {
      int sl = (((r & 1) << 2) + kk * 2 + hh) ^ gkey(line);
      offB[ni][kk] = 16384 + line * 128 + sl * 16;
    }
  }

  QIA(0, 0); QIB(0, 0);
  QIA(1, 1); QIB(1, 1);
  asm volatile("s_waitcnt vmcnt(5)" ::: "memory");
  FULL_BAR();

  int cur = 0, nx2 = 2;
  for (int kt = 0; kt < 128; ++kt) {
    const char* buf = lds[cur];
    const bool pf = (kt + 2) < 128;
    bf16x8 a[4], b[3];
#pragma unroll
    for (int mi = 0; mi < 4; ++mi) a[mi] = *(const bf16x8*)(buf + offA[mi][0]);
#pragma unroll
    for (int ni = 0; ni < 3; ++ni) b[ni] = *(const bf16x8*)(buf + offB[ni][0]);
    if (pf) QIA(kt + 2, nx2);
    FULL_BAR();
    __builtin_amdgcn_s_setprio(1);
#pragma unroll
    for (int mi = 0; mi < 4; ++mi)
#pragma unroll
      for (int ni = 0; ni < 3; ++ni)
        acc[mi][ni] = __builtin_amdgcn_mfma_f32_32x32x16_bf16(a[mi], b[ni], acc[mi][ni], 0, 0, 0);
    __builtin_amdgcn_s_setprio(0);
#pragma unroll
    for (int mi = 0; mi < 4; ++mi) a[mi] = *(const bf16x8*)(buf + offA[mi][1]);
#pragma unroll
    for (int ni = 0; ni < 3; ++ni) b[ni] = *(const bf16x8*)(buf + offB[ni][1]);
    if (pf) {
      QIB(kt + 2, nx2);
      asm volatile("s_waitcnt vmcnt(5)" ::: "memory");
    } else if (kt == 126) {
      asm volatile("s_waitcnt vmcnt(0)" ::: "memory");
    }
    FULL_BAR();
    __builtin_amdgcn_s_setprio(1);
#pragma unroll
    for (int mi = 0; mi < 4; ++mi)
#pragma unroll
      for (int ni = 0; ni < 3; ++ni)
        acc[mi][ni] = __builtin_amdgcn_mfma_f32_32x32x16_bf16(a[mi], b[ni], acc[mi][ni], 0, 0, 0);
    __builtin_amdgcn_s_setprio(0);
    cur = (cur + 1 == 3) ? 0 : cur + 1;
    nx2 = (nx2 + 1 == 3) ? 0 : nx2 + 1;
  }
#undef QIA
#undef QIB

  // epilogue with fused K-rope. C/D: col=lane&31, row=(reg&3)+8*(reg>>2)+4*hh
  float bv[3];
#pragma unroll
  for (int ni = 0; ni < 3; ++ni) bv[ni] = bias[bn + wn * 96 + ni * 32 + l31];
#pragma unroll
  for (int mi = 0; mi < 4; ++mi) {
    int m0 = bm + wm * 128 + mi * 32 + 4 * hh;
#pragma unroll
    for (int reg = 0; reg < 16; ++reg) {
      int row = m0 + (reg & 3) + 8 * (reg >> 2);
      float v0 = acc[mi][0][reg] + bv[0];
      float v1 = acc[mi][1][reg] + bv[1];
      float v2 = acc[mi][2][reg] + bv[2];
      if (wn == 1) {  // K-half0 pair: (ni=1, ni=2), pos = pid[row]
        int p = pid[row];
        float c = cos_t[p * 32 + l31], s = sin_t[p * 32 + l31];
        float x1 = v1, x2 = v2;
        v1 = x1 * c - x2 * s;
        v2 = x2 * c + x1 * s;
      } else if (wn == 2) {  // K-half1 pair: (ni=0, ni=1), pos = pid[S+row]
        int p = pid[S_LEN + row];
        float c = cos_t[p * 32 + l31], s = sin_t[p * 32 + l31];
        float x1 = v0, x2 = v1;
        v0 = x1 * c - x2 * s;
        v1 = x2 * c + x1 * s;
      }
      size_t rb = (size_t)row * N_QKV + bn + wn * 96 + l31;
      outb[rb] = f2bf(v0);
      outb[rb + 32] = f2bf(v1);
      outb[rb + 64] = f2bf(v2);
    }
  }
}

// -------- dense GEMM: 256x128, BK=64, 32x32x16, fp32 W2 (R13-verified) ----
__global__ __launch_bounds__(512, 2) void gemmD(const u16* __restrict__ A,
                                                const float* __restrict__ Bf,
                                                const float* __restrict__ bias,
                                                float* __restrict__ outf) {
  __shared__ __align__(16) char lds[2][49152];

  const int tid = threadIdx.x;
  const int lane = tid & 63, w = tid >> 6;
  const int l31 = lane & 31, hh = lane >> 5;
  const int wm = w >> 1, wn = w & 1;  // 4M x 2N

  int x = blockIdx.x & 7, loc = blockIdx.x >> 3;
  int mb = loc & 7, nb = x * 4 + (loc >> 3);
  const int bm = mb * 256, bn = nb * 128;

  f32x16 acc[2][2];
#pragma unroll
  for (int mi = 0; mi < 2; ++mi)
#pragma unroll
    for (int ni = 0; ni < 2; ++ni)
#pragma unroll
      for (int r = 0; r < 16; ++r) acc[mi][ni][r] = 0.f;

  const size_t K2 = (size_t)KDIM * 2;

  const char* gA[2];
#pragma unroll
  for (int j = 0; j < 2; ++j) {
    int slot = j * 512 + tid;
    int line = slot >> 3;
    int sl = (slot & 7) ^ gkey(line);
    int row = 2 * line + (sl >> 2);
    int colb = (sl & 3) * 16;
    gA[j] = (const char*)A + (size_t)(bm + row) * K2 + colb;
  }
  int bline = tid >> 3;
  int bsl = tid & 7;
  int brow = 2 * bline + (bsl >> 2);
  int bcole = (bsl & 3) * 8;
  const float* gBs = Bf + (size_t)(bn + brow) * KDIM + bcole;
  int bphys = bsl ^ gkey(bline);
  const int bwr = 32768 + bline * 128 + bphys * 16;
  const int ldst = w * 1024;

#define DIA(t, kk)                                                            \
  {                                                                           \
    char* Lb = lds[(t) & 1] + (kk) * 16384;                                   \
    gl2lds16(gA[0] + (size_t)(t) * 128 + (kk) * 64, Lb + ldst);               \
    gl2lds16(gA[1] + (size_t)(t) * 128 + (kk) * 64, Lb + 8192 + ldst);        \
  }
#define DGB(t)                                                                \
  {                                                                           \
    const float* p0 = gBs + (size_t)(t) * 64;                                 \
    b0a = *(const float4*)(p0);                                               \
    b0b = *(const float4*)(p0 + 4);                                           \
    b1a = *(const float4*)(p0 + 32);                                          \
    b1b = *(const float4*)(p0 + 36);                                          \
  }
#define DWB(t)                                                                \
  {                                                                           \
    bf16x8 o0, o1;                                                            \
    o0[0] = (short)f2bf(b0a.x); o0[1] = (short)f2bf(b0a.y);                   \
    o0[2] = (short)f2bf(b0a.z); o0[3] = (short)f2bf(b0a.w);                   \
    o0[4] = (short)f2bf(b0b.x); o0[5] = (short)f2bf(b0b.y);                   \
    o0[6] = (short)f2bf(b0b.z); o0[7] = (short)f2bf(b0b.w);                   \
    o1[0] = (short)f2bf(b1a.x); o1[1] = (short)f2bf(b1a.y);                   \
    o1[2] = (short)f2bf(b1a.z); o1[3] = (short)f2bf(b1a.w);                   \
    o1[4] = (short)f2bf(b1b.x); o1[5] = (short)f2bf(b1b.y);                   \
    o1[6] = (short)f2bf(b1b.z); o1[7] = (short)f2bf(b1b.w);                   \
    char* Lb = lds[(t) & 1];                                                  \
    *(bf16x8*)(Lb + bwr) = o0;                                                \
    *(bf16x8*)(Lb + 8192 + bwr) = o1;                                         \
  }

  int offA[2][2][2], offB[2][2][2];
#pragma unroll
  for (int mi = 0; mi < 2; ++mi) {
    int r = wm * 64 + mi * 32 + l31;
    int line = r >> 1;
#pragma unroll
    for (int kku = 0; kku < 2; ++kku)
#pragma unroll
      for (int st = 0; st < 2; ++st) {
        int sl = (((r & 1) << 2) + st * 2 + hh) ^ gkey(line);
        offA[mi][kku][st] = kku * 16384 + line * 128 + sl * 16;
      }
  }
#pragma unroll
  for (int ni = 0; ni < 2; ++ni) {
    int r = wn * 64 + ni * 32 + l31;
    int line = r >> 1;
#pragma unroll
    for (int kku = 0; kku < 2; ++kku)
#pragma unroll
      for (int st = 0; st < 2; ++st) {
        int sl = (((r & 1) << 2) + st * 2 + hh) ^ gkey(line);
        offB[ni][kku][st] = 32768 + kku * 8192 + line * 128 + sl * 16;
      }
  }

  float4 b0a, b0b, b1a, b1b;
  DGB(0);
  DIA(0, 0);
  DIA(0, 1);
  asm volatile("s_waitcnt vmcnt(4)" ::: "memory");
  DWB(0);
  asm volatile("s_waitcnt vmcnt(0) lgkmcnt(0)" ::: "memory");
  FULL_BAR();

  for (int kt = 0; kt < 64; ++kt) {
    const char* buf = lds[kt & 1];
    const bool pf = (kt + 1) < 64;
    bf16x8 a[2][2], b[2][2];
#pragma unroll
    for (int mi = 0; mi < 2; ++mi)
#pragma unroll
      for (int st = 0; st < 2; ++st) a[mi][st] = *(const bf16x8*)(buf + offA[mi][0][st]);
#pragma unroll
    for (int ni = 0; ni < 2; ++ni)
#pragma unroll
      for (int st = 0; st < 2; ++st) b[ni][st] = *(const bf16x8*)(buf + offB[ni][0][st]);
    if (pf) {
      DIA(kt + 1, 0);
      DGB(kt + 1);
      asm volatile("s_waitcnt vmcnt(6)" ::: "memory");
    } else {
      asm volatile("s_waitcnt vmcnt(0)" ::: "memory");
    }
    FULL_BAR();
    __builtin_amdgcn_s_setprio(1);
#pragma unroll
    for (int st = 0; st < 2; ++st)
#pragma unroll
      for (int mi = 0; mi < 2; ++mi)
#pragma unroll
        for (int ni = 0; ni < 2; ++ni)
          acc[mi][ni] = __builtin_amdgcn_mfma_f32_32x32x16_bf16(a[mi][st], b[ni][st], acc[mi][ni], 0, 0, 0);
    __builtin_amdgcn_s_setprio(0);
#pragma unroll
    for (int mi = 0; mi < 2; ++mi)
#pragma unroll
      for (int st = 0; st < 2; ++st) a[mi][st] = *(const bf16x8*)(buf + offA[mi][1][st]);
#pragma unroll
    for (int ni = 0; ni < 2; ++ni)
#pragma unroll
      for (int st = 0; st < 2; ++st) b[ni][st] = *(const bf16x8*)(buf + offB[ni][1][st]);
    if (pf) {
      DIA(kt + 1, 1);
      asm volatile("s_waitcnt vmcnt(2)" ::: "memory");
      DWB(kt + 1);
      asm volatile("s_waitcnt lgkmcnt(0)" ::: "memory");
    }
    FULL_BAR();
    __builtin_amdgcn_s_setprio(1);
#pragma unroll
    for (int st = 0; st < 2; ++st)
#pragma unroll
      for (int mi = 0; mi < 2; ++mi)
#pragma unroll
        for (int ni = 0; ni < 2; ++ni)
          acc[mi][ni] = __builtin_amdgcn_mfma_f32_32x32x16_bf16(a[mi][st], b[ni][st], acc[mi][ni], 0, 0, 0);
    __builtin_amdgcn_s_setprio(0);
  }
#undef DIA
#undef DGB
#undef DWB

#pragma unroll
  for (int ni = 0; ni < 2; ++ni) {
    int n = bn + wn * 64 + ni * 32 + l31;
    float bv = bias[n];
#pragma unroll
    for (int mi = 0; mi < 2; ++mi) {
      int m0 = bm + wm * 64 + mi * 32 + 4 * hh;
#pragma unroll
      for (int reg = 0; reg < 16; ++reg) {
        int row = m0 + (reg & 3) + 8 * (reg >> 2);
        outf[(size_t)row * HID + n] = acc[mi][ni][reg] + bv;
      }
    }
  }
}

// ------- attention: 8 waves share staged K/V, async-stage, defer-max ------
// (R15-verified structure: 453.9 us total. R16's 4-wave split regressed
// because staging feeds half the q-rows. Do not split below 8 waves.)
__global__ __launch_bounds__(512) void attn_kernel(const u16* __restrict__ mixed,
                                                   const int* __restrict__ pid,
                                                   const float* __restrict__ cos_t,
                                                   const float* __restrict__ sin_t,
                                                   u16* __restrict__ ctx) {
  __shared__ __align__(16) u16 Ksh[2][64 * 136];
  __shared__ __align__(16) u16 Vsh[2][128 * 64];
  __shared__ __align__(16) u16 Pt[8][16 * 72];

  int tid = threadIdx.x;
  int lane = tid & 63, w = tid >> 6;
  int lane15 = lane & 15, g = lane >> 4;

  int bpg = blockIdx.x & 7;
  int h = blockIdx.x >> 3;

  const u16* qp = mixed + (size_t)h * 384;
  const u16* kp = mixed + (size_t)h * 384 + 128;
  const u16* vp = mixed + (size_t)h * 384 + 256;

  int krow = tid >> 3, kc = (tid & 7) * 16;
  int vk0 = 2 * (tid & 31), vd0 = (tid >> 5) * 8;
  f32x4 z4 = {0.f, 0.f, 0.f, 0.f};
  const float QSC = 0.08838834764831845f;
  const float L2E = 1.4426950408889634f;

  bf16x8 kx0, kx1, vr0, vr1;
#define ALOAD(t)                                                              \
  {                                                                           \
    const u16* kr = kp + (size_t)((t)*64 + krow) * RS + kc;                   \
    kx0 = *(const bf16x8*)kr;                                                 \
    kx1 = *(const bf16x8*)(kr + 8);                                           \
    const u16* vr = vp + (size_t)((t)*64 + vk0) * RS + vd0;                   \
    vr0 = *(const bf16x8*)vr;                                                 \
    vr1 = *(const bf16x8*)(vr + RS);                                          \
  }
#define AWRITE(bb)                                                            \
  {                                                                           \
    *(bf16x8*)(&Ksh[bb][krow * 136 + kc]) = kx0;                              \
    *(bf16x8*)(&Ksh[bb][krow * 136 + kc + 8]) = kx1;                          \
    _Pragma("unroll") for (int jj = 0; jj < 8; ++jj) {                        \
      int d = vd0 + jj;                                                       \
      u32 val = (u32)(u16)vr0[jj] | ((u32)(u16)vr1[jj] << 16);                \
      *(u32*)((char*)Vsh[bb] + d * 128 + (((vk0 >> 3) ^ (d & 7)) << 4) +      \
              (vk0 & 7) * 2) = val;                                           \
    }                                                                         \
  }

  for (int pass = 0; pass < 2; ++pass) {
    int pg = pass ? (15 - bpg) : bpg;
    int qi = 2 * pg + (w >> 2);
    int qrow = qi * 64 + (w & 3) * 16 + lane15;
    int ntiles = 2 * pg + 2;

    bf16x8 qf[4];
    const u16* qptr = qp + (size_t)qrow * RS + g * 8;
#pragma unroll
    for (int d0 = 0; d0 < 4; ++d0) qf[d0] = *(const bf16x8*)(qptr + d0 * 32);
    {
      int p1 = pid[qrow], p2 = pid[S_LEN + qrow];
      float cc[8], ss[8], dd[8], tt[8];
#pragma unroll
      for (int j = 0; j < 8; ++j) {
        cc[j] = cos_t[p1 * 32 + g * 8 + j];
        ss[j] = sin_t[p1 * 32 + g * 8 + j];
        dd[j] = cos_t[p2 * 32 + g * 8 + j];
        tt[j] = sin_t[p2 * 32 + g * 8 + j];
      }
#pragma unroll
      for (int j = 0; j < 8; ++j) {
        float x1 = bf2f((u16)qf[0][j]), x2 = bf2f((u16)qf[1][j]);
        qf[0][j] = (short)f2bf((x1 * cc[j] - x2 * ss[j]) * QSC);
        qf[1][j] = (short)f2bf((x2 * cc[j] + x1 * ss[j]) * QSC);
        float y1 = bf2f((u16)qf[2][j]), y2 = bf2f((u16)qf[3][j]);
        qf[2][j] = (short)f2bf((y1 * dd[j] - y2 * tt[j]) * QSC);
        qf[3][j] = (short)f2bf((y2 * dd[j] + y1 * tt[j]) * QSC);
      }
    }

    f32x4 pv[8];
#pragma unroll
    for (int db = 0; db < 8; ++db) pv[db] = z4;
    float m_run = -1e30f, l_run = 0.0f;

    ALOAD(0);
    AWRITE(0);
    __syncthreads();

    for (int t = 0; t < ntiles; ++t) {
      const u16* Kc = Ksh[t & 1];
      const char* Vc = (const char*)Vsh[t & 1];
      if (t + 1 < ntiles) ALOAD(t + 1);

      int kb0 = t * 64;
      f32x4 sa[4];
#pragma unroll
      for (int kt16 = 0; kt16 < 4; ++kt16) sa[kt16] = z4;
#pragma unroll
      for (int kt16 = 0; kt16 < 4; ++kt16)
#pragma unroll
        for (int d0 = 0; d0 < 4; ++d0) {
          bf16x8 kf = *(const bf16x8*)(Kc + (kt16 * 16 + lane15) * 136 + d0 * 32 + g * 8);
          sa[kt16] = __builtin_amdgcn_mfma_f32_16x16x32_bf16(kf, qf[d0], sa[kt16], 0, 0, 0);
        }
      float s[16];
#pragma unroll
      for (int kt16 = 0; kt16 < 4; ++kt16)
#pragma unroll
        for (int rr = 0; rr < 4; ++rr) {
          int kg = kb0 + kt16 * 16 + 4 * g + rr;
          s[kt16 * 4 + rr] = (kg > qrow) ? -1e30f : sa[kt16][rr];
        }
      float mx = s[0];
#pragma unroll
      for (int i2 = 1; i2 < 16; ++i2) mx = fmaxf(mx, s[i2]);
      mx = fmaxf(mx, __shfl_xor(mx, 16));
      mx = fmaxf(mx, __shfl_xor(mx, 32));
      if (!__all(mx - m_run <= 8.0f)) {
        float mnew = fmaxf(m_run, mx);
        float fac = exp2f((m_run - mnew) * L2E);
        l_run *= fac;
#pragma unroll
        for (int db = 0; db < 8; ++db) pv[db] *= fac;
        m_run = mnew;
      }
      float p[16], psum = 0.f;
#pragma unroll
      for (int i2 = 0; i2 < 16; ++i2) {
        p[i2] = exp2f((s[i2] - m_run) * L2E);
        psum += p[i2];
      }
      psum += __shfl_xor(psum, 16);
      psum += __shfl_xor(psum, 32);
      l_run += psum;

#pragma unroll
      for (int kt16 = 0; kt16 < 4; ++kt16) {
        u32x2 pw;
        pw.x = (u32)f2bf(p[kt16 * 4 + 0]) | ((u32)f2bf(p[kt16 * 4 + 1]) << 16);
        pw.y = (u32)f2bf(p[kt16 * 4 + 2]) | ((u32)f2bf(p[kt16 * 4 + 3]) << 16);
        *(u32x2*)(&Pt[w][lane15 * 72 + kt16 * 16 + 4 * g]) = pw;
      }
      asm volatile("s_waitcnt lgkmcnt(0)" ::: "memory");
      bf16x8 pf0 = *(const bf16x8*)(&Pt[w][lane15 * 72 + 8 * g]);
      bf16x8 pf1 = *(const bf16x8*)(&Pt[w][lane15 * 72 + 32 + 8 * g]);

#pragma unroll
      for (int db = 0; db < 8; ++db) {
        int d = db * 16 + lane15;
        bf16x8 vf0 = *(const bf16x8*)(Vc + d * 128 + ((g ^ (d & 7)) << 4));
        bf16x8 vf1 = *(const bf16x8*)(Vc + d * 128 + (((4 + g) ^ (d & 7)) << 4));
        pv[db] = __builtin_amdgcn_mfma_f32_16x16x32_bf16(vf0, pf0, pv[db], 0, 0, 0);
        pv[db] = __builtin_amdgcn_mfma_f32_16x16x32_bf16(vf1, pf1, pv[db], 0, 0, 0);
      }

      if (t + 1 < ntiles) AWRITE((t + 1) & 1);
      __syncthreads();
    }

    float inv = 1.0f / l_run;
#pragma unroll
    for (int db = 0; db < 8; ++db) {
      ushort4 o;
      o.x = f2bf(pv[db][0] * inv);
      o.y = f2bf(pv[db][1] * inv);
      o.z = f2bf(pv[db][2] * inv);
      o.w = f2bf(pv[db][3] * inv);
      *(ushort4*)(ctx + (size_t)qrow * HID + h * HDD + db * 16 + 4 * g) = o;
    }
    __syncthreads();
  }
#undef ALOAD
#undef AWRITE
}

// ---------------- launcher -------------------------------------------------
extern "C" void kernel_launch(void* const* d_in, const int* in_sizes, int n_in,
                              void* d_out, int out_size, void* d_ws, size_t ws_size,
                              hipStream_t stream) {
  const float* hidden = (const float*)d_in[0];
  const int* pid = (const int*)d_in[1];
  const float* wqkv = (const float*)d_in[3];
  const float* bqkv = (const float*)d_in[4];
  const float* wdense = (const float*)d_in[5];
  const float* bdense = (const float*)d_in[6];
  float* out = (float*)d_out;

  char* ws = (char*)d_ws;
  u16* W1 = (u16*)ws;                        // [12288][4096] bf16
  u16* X = (u16*)(ws + 134217728);           // [2048][4096] bf16
  u16* mixed = (u16*)(ws + 150994944);       // [2048][12288] bf16
  u16* ctx = (u16*)(ws + 201326592);         // [2048][4096] bf16
  float* cos_t = (float*)(ws + 218103808);
  float* sin_t = (float*)(ws + 218365952);

  cvt3_kernel<<<dim3(2048), dim3(256), 0, stream>>>(
      wqkv, W1, N_QKV * KDIM / 4, hidden, X, S_LEN * HID / 4, cos_t, sin_t);

  // QKV with fused K-rope in epilogue (ropek kernel eliminated)
  gemmQ<<<dim3(256), dim3(512), 0, stream>>>(X, W1, bqkv, pid, cos_t, sin_t, mixed);

  // attention: R15-verified 8-wave shared-staging structure
  attn_kernel<<<dim3(256), dim3(512), 0, stream>>>(mixed, pid, cos_t, sin_t, ctx);

  gemmD<<<dim3(256), dim3(512), 0, stream>>>(ctx, wdense, bdense, out);
}

// Round 18
// 453.750 us; speedup vs baseline: 1.0393x; 1.0393x over previous
//
#include <hip/hip_runtime.h>

typedef unsigned short u16;
typedef unsigned int u32;
typedef __attribute__((ext_vector_type(4))) float f32x4;
typedef __attribute__((ext_vector_type(16))) float f32x16;
typedef __attribute__((ext_vector_type(8))) short bf16x8;
typedef __attribute__((ext_vector_type(2))) unsigned int u32x2;

#define S_LEN 2048
#define NHEAD 32
#define HDD 128
#define HID 4096
#define N_QKV 12288
#define KDIM 4096
#define RS 12288  // mixed row stride (elements)

__device__ __forceinline__ u16 f2bf(float f) {
  u32 u = __builtin_bit_cast(u32, f);
  u = (u + 0x7FFFu + ((u >> 16) & 1u)) >> 16;
  return (u16)u;
}
__device__ __forceinline__ float bf2f(u16 h) {
  u32 u = ((u32)h) << 16;
  return __builtin_bit_cast(float, u);
}

// Gray-key slot swizzle (R13-verified: 0 bank conflicts with 32x32 frags)
__device__ __forceinline__ int gkey(int line) { return (line ^ (line >> 1)) & 7; }

__device__ __forceinline__ void gl2lds16(const void* g, void* l) {
  __builtin_amdgcn_global_load_lds(
      (const __attribute__((address_space(1))) u32*)g,
      (__attribute__((address_space(3))) u32*)l, 16, 0, 0);
}

#define FULL_BAR()                          \
  {                                         \
    asm volatile("" ::: "memory");          \
    __builtin_amdgcn_s_barrier();           \
    asm volatile("" ::: "memory");          \
  }

// ------ fused fp32 -> bf16 conversion (W1, X) + RoPE trig tables ----------
__global__ __launch_bounds__(256) void cvt3_kernel(const float* __restrict__ s0, u16* __restrict__ d0, int n0,
                                                   const float* __restrict__ s2, u16* __restrict__ d2, int n2,
                                                   float* __restrict__ cos_t, float* __restrict__ sin_t) {
  int i = blockIdx.x * blockDim.x + threadIdx.x;
  if (i < S_LEN * 32) {
    int s = i >> 5, ii = i & 31;
    float invf = expf(-0.28782313662425572f * (float)ii);
    float a = (float)s * invf;
    cos_t[i] = cosf(a);
    sin_t[i] = sinf(a);
  }
  int st = gridDim.x * blockDim.x;
  int ntot = n0 + n2;
  for (; i < ntot; i += st) {
    const float* s;
    u16* d;
    int j = i;
    if (j < n0) {
      s = s0; d = d0;
    } else {
      j -= n0; s = s2; d = d2;
    }
    float4 v = ((const float4*)s)[j];
    u32x2 o;
    o.x = (u32)f2bf(v.x) | ((u32)f2bf(v.y) << 16);
    o.y = (u32)f2bf(v.z) | ((u32)f2bf(v.w) << 16);
    ((u32x2*)d)[j] = o;
  }
}

// ---------------- standalone K-rope (K columns of mixed only) -------------
// R17 lesson: fusing this into gemmQ's epilogue cost 36 us (uncoalesced
// per-reg trig loads) vs the ~6 us this kernel costs. Keep it standalone.
__global__ __launch_bounds__(256) void ropek_kernel(u16* __restrict__ mixed,
                                                    const int* __restrict__ pid,
                                                    const float* __restrict__ cos_t,
                                                    const float* __restrict__ sin_t) {
  int idx = blockIdx.x * blockDim.x + threadIdx.x;
  const int total = NHEAD * S_LEN * 2 * 8;  // 2^20
  if (idx >= total) return;
  int j = idx & 7;
  int half = (idx >> 3) & 1;
  int s = (idx >> 4) & (S_LEN - 1);
  int h = idx >> 15;
  int i0 = j * 4;
  int p = pid[half * S_LEN + s];
  float4 c4 = *(const float4*)(cos_t + p * 32 + i0);
  float4 s4 = *(const float4*)(sin_t + p * 32 + i0);
  u16* base = mixed + (size_t)s * RS + h * 384 + 128 + half * 64 + i0;
  ushort4 x1v = *(const ushort4*)(base);
  ushort4 x2v = *(const ushort4*)(base + 32);
  ushort4 o1, o2;
  {
    float x1 = bf2f(x1v.x), x2 = bf2f(x2v.x);
    o1.x = f2bf(x1 * c4.x - x2 * s4.x);
    o2.x = f2bf(x2 * c4.x + x1 * s4.x);
  }
  {
    float x1 = bf2f(x1v.y), x2 = bf2f(x2v.y);
    o1.y = f2bf(x1 * c4.y - x2 * s4.y);
    o2.y = f2bf(x2 * c4.y + x1 * s4.y);
  }
  {
    float x1 = bf2f(x1v.z), x2 = bf2f(x2v.z);
    o1.z = f2bf(x1 * c4.z - x2 * s4.z);
    o2.z = f2bf(x2 * c4.z + x1 * s4.z);
  }
  {
    float x1 = bf2f(x1v.w), x2 = bf2f(x2v.w);
    o1.w = f2bf(x1 * c4.w - x2 * s4.w);
    o2.w = f2bf(x2 * c4.w + x1 * s4.w);
  }
  *(ushort4*)(base) = o1;
  *(ushort4*)(base + 32) = o2;
}

// -------- QKV GEMM: 256x384, BK=32, ring-3, 32x32x16, Gray-key ------------
// (R13/R15-verified: ~184 us, MfmaUtil 54, 0 bank conflicts; LDS-port-bound
// structural ceiling ~64% — frozen)
__global__ __launch_bounds__(512, 2) void gemmQ(const u16* __restrict__ A,
                                                const u16* __restrict__ B,
                                                const float* __restrict__ bias,
                                                u16* __restrict__ outb) {
  __shared__ __align__(16) char lds[3][40960];

  const int tid = threadIdx.x;
  const int lane = tid & 63, w = tid >> 6;
  const int l31 = lane & 31, hh = lane >> 5;
  const int wm = w >> 2, wn = w & 3;  // 2M x 4N

  int x = blockIdx.x & 7, loc = blockIdx.x >> 3;
  int mb = loc & 7, nb = x * 4 + (loc >> 3);
  const int bm = mb * 256, bn = nb * 384;

  f32x16 acc[4][3];
#pragma unroll
  for (int mi = 0; mi < 4; ++mi)
#pragma unroll
    for (int ni = 0; ni < 3; ++ni)
#pragma unroll
      for (int r = 0; r < 16; ++r) acc[mi][ni][r] = 0.f;

  const size_t K2 = (size_t)KDIM * 2;

  const char* gA[2];
#pragma unroll
  for (int j = 0; j < 2; ++j) {
    int slot = j * 512 + tid;
    int line = slot >> 3;
    int sl = (slot & 7) ^ gkey(line);
    int row = 2 * line + (sl >> 2);
    int colb = (sl & 3) * 16;
    gA[j] = (const char*)A + (size_t)(bm + row) * K2 + colb;
  }
  const char* gB[3];
#pragma unroll
  for (int j = 0; j < 3; ++j) {
    int slot = j * 512 + tid;
    int line = slot >> 3;
    int sl = (slot & 7) ^ gkey(line);
    int row = 2 * line + (sl >> 2);
    int colb = (sl & 3) * 16;
    gB[j] = (const char*)B + (size_t)(bn + row) * K2 + colb;
  }
  const int ldst = w * 1024;

#define QIA(t, bi)                                                  \
  {                                                                 \
    char* Lb = lds[bi];                                             \
    gl2lds16(gA[0] + (size_t)(t) * 64, Lb + ldst);                  \
    gl2lds16(gA[1] + (size_t)(t) * 64, Lb + 8192 + ldst);           \
  }
#define QIB(t, bi)                                                  \
  {                                                                 \
    char* Lb = lds[bi] + 16384;                                     \
    _Pragma("unroll")                                               \
    for (int j = 0; j < 3; ++j)                                     \
      gl2lds16(gB[j] + (size_t)(t) * 64, Lb + j * 8192 + ldst);     \
  }

  int offA[4][2], offB[3][2];
#pragma unroll
  for (int mi = 0; mi < 4; ++mi) {
    int r = wm * 128 + mi * 32 + l31;
    int line = r >> 1;
#pragma unroll
    for (int kk = 0; kk < 2; ++kk) {
      int sl = (((r & 1) << 2) + kk * 2 + hh) ^ gkey(line);
      offA[mi][kk] = line * 128 + sl * 16;
    }
  }
#pragma unroll
  for (int ni = 0; ni < 3; ++ni) {
    int r = wn * 96 + ni * 32 + l31;
    int line = r >> 1;
#pragma unroll
    for (int kk = 0; kk < 2; ++kk) {
      int sl = (((r & 1) << 2) + kk * 2 + hh) ^ gkey(line);
      offB[ni][kk] = 16384 + line * 128 + sl * 16;
    }
  }

  QIA(0, 0); QIB(0, 0);
  QIA(1, 1); QIB(1, 1);
  asm volatile("s_waitcnt vmcnt(5)" ::: "memory");
  FULL_BAR();

  int cur = 0, nx2 = 2;
  for (int kt = 0; kt < 128; ++kt) {
    const char* buf = lds[cur];
    const bool pf = (kt + 2) < 128;
    bf16x8 a[4], b[3];
#pragma unroll
    for (int mi = 0; mi < 4; ++mi) a[mi] = *(const bf16x8*)(buf + offA[mi][0]);
#pragma unroll
    for (int ni = 0; ni < 3; ++ni) b[ni] = *(const bf16x8*)(buf + offB[ni][0]);
    if (pf) QIA(kt + 2, nx2);
    FULL_BAR();
    __builtin_amdgcn_s_setprio(1);
#pragma unroll
    for (int mi = 0; mi < 4; ++mi)
#pragma unroll
      for (int ni = 0; ni < 3; ++ni)
        acc[mi][ni] = __builtin_amdgcn_mfma_f32_32x32x16_bf16(a[mi], b[ni], acc[mi][ni], 0, 0, 0);
    __builtin_amdgcn_s_setprio(0);
#pragma unroll
    for (int mi = 0; mi < 4; ++mi) a[mi] = *(const bf16x8*)(buf + offA[mi][1]);
#pragma unroll
    for (int ni = 0; ni < 3; ++ni) b[ni] = *(const bf16x8*)(buf + offB[ni][1]);
    if (pf) {
      QIB(kt + 2, nx2);
      asm volatile("s_waitcnt vmcnt(5)" ::: "memory");
    } else if (kt == 126) {
      asm volatile("s_waitcnt vmcnt(0)" ::: "memory");
    }
    FULL_BAR();
    __builtin_amdgcn_s_setprio(1);
#pragma unroll
    for (int mi = 0; mi < 4; ++mi)
#pragma unroll
      for (int ni = 0; ni < 3; ++ni)
        acc[mi][ni] = __builtin_amdgcn_mfma_f32_32x32x16_bf16(a[mi], b[ni], acc[mi][ni], 0, 0, 0);
    __builtin_amdgcn_s_setprio(0);
    cur = (cur + 1 == 3) ? 0 : cur + 1;
    nx2 = (nx2 + 1 == 3) ? 0 : nx2 + 1;
  }
#undef QIA
#undef QIB

#pragma unroll
  for (int ni = 0; ni < 3; ++ni) {
    int n = bn + wn * 96 + ni * 32 + l31;
    float bv = bias[n];
#pragma unroll
    for (int mi = 0; mi < 4; ++mi) {
      int m0 = bm + wm * 128 + mi * 32 + 4 * hh;
#pragma unroll
      for (int reg = 0; reg < 16; ++reg) {
        int row = m0 + (reg & 3) + 8 * (reg >> 2);
        outb[(size_t)row * N_QKV + n] = f2bf(acc[mi][ni][reg] + bv);
      }
    }
  }
}

// -------- dense GEMM: 256x128, BK=64, 32x32x16, fp32 W2 (R13-verified) ----
__global__ __launch_bounds__(512, 2) void gemmD(const u16* __restrict__ A,
                                                const float* __restrict__ Bf,
                                                const float* __restrict__ bias,
                                                float* __restrict__ outf) {
  __shared__ __align__(16) char lds[2][49152];

  const int tid = threadIdx.x;
  const int lane = tid & 63, w = tid >> 6;
  const int l31 = lane & 31, hh = lane >> 5;
  const int wm = w >> 1, wn = w & 1;  // 4M x 2N

  int x = blockIdx.x & 7, loc = blockIdx.x >> 3;
  int mb = loc & 7, nb = x * 4 + (loc >> 3);
  const int bm = mb * 256, bn = nb * 128;

  f32x16 acc[2][2];
#pragma unroll
  for (int mi = 0; mi < 2; ++mi)
#pragma unroll
    for (int ni = 0; ni < 2; ++ni)
#pragma unroll
      for (int r = 0; r < 16; ++r) acc[mi][ni][r] = 0.f;

  const size_t K2 = (size_t)KDIM * 2;

  const char* gA[2];
#pragma unroll
  for (int j = 0; j < 2; ++j) {
    int slot = j * 512 + tid;
    int line = slot >> 3;
    int sl = (slot & 7) ^ gkey(line);
    int row = 2 * line + (sl >> 2);
    int colb = (sl & 3) * 16;
    gA[j] = (const char*)A + (size_t)(bm + row) * K2 + colb;
  }
  int bline = tid >> 3;
  int bsl = tid & 7;
  int brow = 2 * bline + (bsl >> 2);
  int bcole = (bsl & 3) * 8;
  const float* gBs = Bf + (size_t)(bn + brow) * KDIM + bcole;
  int bphys = bsl ^ gkey(bline);
  const int bwr = 32768 + bline * 128 + bphys * 16;
  const int ldst = w * 1024;

#define DIA(t, kk)                                                            \
  {                                                                           \
    char* Lb = lds[(t) & 1] + (kk) * 16384;                                   \
    gl2lds16(gA[0] + (size_t)(t) * 128 + (kk) * 64, Lb + ldst);               \
    gl2lds16(gA[1] + (size_t)(t) * 128 + (kk) * 64, Lb + 8192 + ldst);        \
  }
#define DGB(t)                                                                \
  {                                                                           \
    const float* p0 = gBs + (size_t)(t) * 64;                                 \
    b0a = *(const float4*)(p0);                                               \
    b0b = *(const float4*)(p0 + 4);                                           \
    b1a = *(const float4*)(p0 + 32);                                          \
    b1b = *(const float4*)(p0 + 36);                                          \
  }
#define DWB(t)                                                                \
  {                                                                           \
    bf16x8 o0, o1;                                                            \
    o0[0] = (short)f2bf(b0a.x); o0[1] = (short)f2bf(b0a.y);                   \
    o0[2] = (short)f2bf(b0a.z); o0[3] = (short)f2bf(b0a.w);                   \
    o0[4] = (short)f2bf(b0b.x); o0[5] = (short)f2bf(b0b.y);                   \
    o0[6] = (short)f2bf(b0b.z); o0[7] = (short)f2bf(b0b.w);                   \
    o1[0] = (short)f2bf(b1a.x); o1[1] = (short)f2bf(b1a.y);                   \
    o1[2] = (short)f2bf(b1a.z); o1[3] = (short)f2bf(b1a.w);                   \
    o1[4] = (short)f2bf(b1b.x); o1[5] = (short)f2bf(b1b.y);                   \
    o1[6] = (short)f2bf(b1b.z); o1[7] = (short)f2bf(b1b.w);                   \
    char* Lb = lds[(t) & 1];                                                  \
    *(bf16x8*)(Lb + bwr) = o0;                                                \
    *(bf16x8*)(Lb + 8192 + bwr) = o1;                                         \
  }

  int offA[2][2][2], offB[2][2][2];
#pragma unroll
  for (int mi = 0; mi < 2; ++mi) {
    int r = wm * 64 + mi * 32 + l31;
    int line = r >> 1;
#pragma unroll
    for (int kku = 0; kku < 2; ++kku)
#pragma unroll
      for (int st = 0; st < 2; ++st) {
        int sl = (((r & 1) << 2) + st * 2 + hh) ^ gkey(line);
        offA[mi][kku][st] = kku * 16384 + line * 128 + sl * 16;
      }
  }
#pragma unroll
  for (int ni = 0; ni < 2; ++ni) {
    int r = wn * 64 + ni * 32 + l31;
    int line = r >> 1;
#pragma unroll
    for (int kku = 0; kku < 2; ++kku)
#pragma unroll
      for (int st = 0; st < 2; ++st) {
        int sl = (((r & 1) << 2) + st * 2 + hh) ^ gkey(line);
        offB[ni][kku][st] = 32768 + kku * 8192 + line * 128 + sl * 16;
      }
  }

  float4 b0a, b0b, b1a, b1b;
  DGB(0);
  DIA(0, 0);
  DIA(0, 1);
  asm volatile("s_waitcnt vmcnt(4)" ::: "memory");
  DWB(0);
  asm volatile("s_waitcnt vmcnt(0) lgkmcnt(0)" ::: "memory");
  FULL_BAR();

  for (int kt = 0; kt < 64; ++kt) {
    const char* buf = lds[kt & 1];
    const bool pf = (kt + 1) < 64;
    bf16x8 a[2][2], b[2][2];
#pragma unroll
    for (int mi = 0; mi < 2; ++mi)
#pragma unroll
      for (int st = 0; st < 2; ++st) a[mi][st] = *(const bf16x8*)(buf + offA[mi][0][st]);
#pragma unroll
    for (int ni = 0; ni < 2; ++ni)
#pragma unroll
      for (int st = 0; st < 2; ++st) b[ni][st] = *(const bf16x8*)(buf + offB[ni][0][st]);
    if (pf) {
      DIA(kt + 1, 0);
      DGB(kt + 1);
      asm volatile("s_waitcnt vmcnt(6)" ::: "memory");
    } else {
      asm volatile("s_waitcnt vmcnt(0)" ::: "memory");
    }
    FULL_BAR();
    __builtin_amdgcn_s_setprio(1);
#pragma unroll
    for (int st = 0; st < 2; ++st)
#pragma unroll
      for (int mi = 0; mi < 2; ++mi)
#pragma unroll
        for (int ni = 0; ni < 2; ++ni)
          acc[mi][ni] = __builtin_amdgcn_mfma_f32_32x32x16_bf16(a[mi][st], b[ni][st], acc[mi][ni], 0, 0, 0);
    __builtin_amdgcn_s_setprio(0);
#pragma unroll
    for (int mi = 0; mi < 2; ++mi)
#pragma unroll
      for (int st = 0; st < 2; ++st) a[mi][st] = *(const bf16x8*)(buf + offA[mi][1][st]);
#pragma unroll
    for (int ni = 0; ni < 2; ++ni)
#pragma unroll
      for (int st = 0; st < 2; ++st) b[ni][st] = *(const bf16x8*)(buf + offB[ni][1][st]);
    if (pf) {
      DIA(kt + 1, 1);
      asm volatile("s_waitcnt vmcnt(2)" ::: "memory");
      DWB(kt + 1);
      asm volatile("s_waitcnt lgkmcnt(0)" ::: "memory");
    }
    FULL_BAR();
    __builtin_amdgcn_s_setprio(1);
#pragma unroll
    for (int st = 0; st < 2; ++st)
#pragma unroll
      for (int mi = 0; mi < 2; ++mi)
#pragma unroll
        for (int ni = 0; ni < 2; ++ni)
          acc[mi][ni] = __builtin_amdgcn_mfma_f32_32x32x16_bf16(a[mi][st], b[ni][st], acc[mi][ni], 0, 0, 0);
    __builtin_amdgcn_s_setprio(0);
  }
#undef DIA
#undef DGB
#undef DWB

#pragma unroll
  for (int ni = 0; ni < 2; ++ni) {
    int n = bn + wn * 64 + ni * 32 + l31;
    float bv = bias[n];
#pragma unroll
    for (int mi = 0; mi < 2; ++mi) {
      int m0 = bm + wm * 64 + mi * 32 + 4 * hh;
#pragma unroll
      for (int reg = 0; reg < 16; ++reg) {
        int row = m0 + (reg & 3) + 8 * (reg >> 2);
        outf[(size_t)row * HID + n] = acc[mi][ni][reg] + bv;
      }
    }
  }
}

// ------- attention: 8 waves share staged K/V, async-stage, defer-max ------
// R15-verified structure. Grid decode flipped to h = bid&31, bpg = bid>>5:
// the 8 blocks sharing a head's K/V are all == h (mod 8) -> same XCD under
// round-robin dispatch; each XCD L2 (4MB) holds its 4 heads' K/V exactly.
__global__ __launch_bounds__(512) void attn_kernel(const u16* __restrict__ mixed,
                                                   const int* __restrict__ pid,
                                                   const float* __restrict__ cos_t,
                                                   const float* __restrict__ sin_t,
                                                   u16* __restrict__ ctx) {
  __shared__ __align__(16) u16 Ksh[2][64 * 136];
  __shared__ __align__(16) u16 Vsh[2][128 * 64];
  __shared__ __align__(16) u16 Pt[8][16 * 72];

  int tid = threadIdx.x;
  int lane = tid & 63, w = tid >> 6;
  int lane15 = lane & 15, g = lane >> 4;

  int h = blockIdx.x & 31;    // head (same-h blocks -> same XCD slot)
  int bpg = blockIdx.x >> 5;  // pair-group id 0..7

  const u16* qp = mixed + (size_t)h * 384;
  const u16* kp = mixed + (size_t)h * 384 + 128;
  const u16* vp = mixed + (size_t)h * 384 + 256;

  int krow = tid >> 3, kc = (tid & 7) * 16;
  int vk0 = 2 * (tid & 31), vd0 = (tid >> 5) * 8;
  f32x4 z4 = {0.f, 0.f, 0.f, 0.f};
  const float QSC = 0.08838834764831845f;
  const float L2E = 1.4426950408889634f;

  bf16x8 kx0, kx1, vr0, vr1;
#define ALOAD(t)                                                              \
  {                                                                           \
    const u16* kr = kp + (size_t)((t)*64 + krow) * RS + kc;                   \
    kx0 = *(const bf16x8*)kr;                                                 \
    kx1 = *(const bf16x8*)(kr + 8);                                           \
    const u16* vr = vp + (size_t)((t)*64 + vk0) * RS + vd0;                   \
    vr0 = *(const bf16x8*)vr;                                                 \
    vr1 = *(const bf16x8*)(vr + RS);                                          \
  }
#define AWRITE(bb)                                                            \
  {                                                                           \
    *(bf16x8*)(&Ksh[bb][krow * 136 + kc]) = kx0;                              \
    *(bf16x8*)(&Ksh[bb][krow * 136 + kc + 8]) = kx1;                          \
    _Pragma("unroll") for (int jj = 0; jj < 8; ++jj) {                        \
      int d = vd0 + jj;                                                       \
      u32 val = (u32)(u16)vr0[jj] | ((u32)(u16)vr1[jj] << 16);                \
      *(u32*)((char*)Vsh[bb] + d * 128 + (((vk0 >> 3) ^ (d & 7)) << 4) +      \
              (vk0 & 7) * 2) = val;                                           \
    }                                                                         \
  }

  for (int pass = 0; pass < 2; ++pass) {
    int pg = pass ? (15 - bpg) : bpg;
    int qi = 2 * pg + (w >> 2);
    int qrow = qi * 64 + (w & 3) * 16 + lane15;
    int ntiles = 2 * pg + 2;

    bf16x8 qf[4];
    const u16* qptr = qp + (size_t)qrow * RS + g * 8;
#pragma unroll
    for (int d0 = 0; d0 < 4; ++d0) qf[d0] = *(const bf16x8*)(qptr + d0 * 32);
    {
      int p1 = pid[qrow], p2 = pid[S_LEN + qrow];
      float cc[8], ss[8], dd[8], tt[8];
#pragma unroll
      for (int j = 0; j < 8; ++j) {
        cc[j] = cos_t[p1 * 32 + g * 8 + j];
        ss[j] = sin_t[p1 * 32 + g * 8 + j];
        dd[j] = cos_t[p2 * 32 + g * 8 + j];
        tt[j] = sin_t[p2 * 32 + g * 8 + j];
      }
#pragma unroll
      for (int j = 0; j < 8; ++j) {
        float x1 = bf2f((u16)qf[0][j]), x2 = bf2f((u16)qf[1][j]);
        qf[0][j] = (short)f2bf((x1 * cc[j] - x2 * ss[j]) * QSC);
        qf[1][j] = (short)f2bf((x2 * cc[j] + x1 * ss[j]) * QSC);
        float y1 = bf2f((u16)qf[2][j]), y2 = bf2f((u16)qf[3][j]);
        qf[2][j] = (short)f2bf((y1 * dd[j] - y2 * tt[j]) * QSC);
        qf[3][j] = (short)f2bf((y2 * dd[j] + y1 * tt[j]) * QSC);
      }
    }

    f32x4 pv[8];
#pragma unroll
    for (int db = 0; db < 8; ++db) pv[db] = z4;
    float m_run = -1e30f, l_run = 0.0f;

    ALOAD(0);
    AWRITE(0);
    __syncthreads();

    for (int t = 0; t < ntiles; ++t) {
      const u16* Kc = Ksh[t & 1];
      const char* Vc = (const char*)Vsh[t & 1];
      if (t + 1 < ntiles) ALOAD(t + 1);

      int kb0 = t * 64;
      f32x4 sa[4];
#pragma unroll
      for (int kt16 = 0; kt16 < 4; ++kt16) sa[kt16] = z4;
#pragma unroll
      for (int kt16 = 0; kt16 < 4; ++kt16)
#pragma unroll
        for (int d0 = 0; d0 < 4; ++d0) {
          bf16x8 kf = *(const bf16x8*)(Kc + (kt16 * 16 + lane15) * 136 + d0 * 32 + g * 8);
          sa[kt16] = __builtin_amdgcn_mfma_f32_16x16x32_bf16(kf, qf[d0], sa[kt16], 0, 0, 0);
        }
      float s[16];
#pragma unroll
      for (int kt16 = 0; kt16 < 4; ++kt16)
#pragma unroll
        for (int rr = 0; rr < 4; ++rr) {
          int kg = kb0 + kt16 * 16 + 4 * g + rr;
          s[kt16 * 4 + rr] = (kg > qrow) ? -1e30f : sa[kt16][rr];
        }
      float mx = s[0];
#pragma unroll
      for (int i2 = 1; i2 < 16; ++i2) mx = fmaxf(mx, s[i2]);
      mx = fmaxf(mx, __shfl_xor(mx, 16));
      mx = fmaxf(mx, __shfl_xor(mx, 32));
      if (!__all(mx - m_run <= 8.0f)) {
        float mnew = fmaxf(m_run, mx);
        float fac = exp2f((m_run - mnew) * L2E);
        l_run *= fac;
#pragma unroll
        for (int db = 0; db < 8; ++db) pv[db] *= fac;
        m_run = mnew;
      }
      float p[16], psum = 0.f;
#pragma unroll
      for (int i2 = 0; i2 < 16; ++i2) {
        p[i2] = exp2f((s[i2] - m_run) * L2E);
        psum += p[i2];
      }
      psum += __shfl_xor(psum, 16);
      psum += __shfl_xor(psum, 32);
      l_run += psum;

#pragma unroll
      for (int kt16 = 0; kt16 < 4; ++kt16) {
        u32x2 pw;
        pw.x = (u32)f2bf(p[kt16 * 4 + 0]) | ((u32)f2bf(p[kt16 * 4 + 1]) << 16);
        pw.y = (u32)f2bf(p[kt16 * 4 + 2]) | ((u32)f2bf(p[kt16 * 4 + 3]) << 16);
        *(u32x2*)(&Pt[w][lane15 * 72 + kt16 * 16 + 4 * g]) = pw;
      }
      asm volatile("s_waitcnt lgkmcnt(0)" ::: "memory");
      bf16x8 pf0 = *(const bf16x8*)(&Pt[w][lane15 * 72 + 8 * g]);
      bf16x8 pf1 = *(const bf16x8*)(&Pt[w][lane15 * 72 + 32 + 8 * g]);

#pragma unroll
      for (int db = 0; db < 8; ++db) {
        int d = db * 16 + lane15;
        bf16x8 vf0 = *(const bf16x8*)(Vc + d * 128 + ((g ^ (d & 7)) << 4));
        bf16x8 vf1 = *(const bf16x8*)(Vc + d * 128 + (((4 + g) ^ (d & 7)) << 4));
        pv[db] = __builtin_amdgcn_mfma_f32_16x16x32_bf16(vf0, pf0, pv[db], 0, 0, 0);
        pv[db] = __builtin_amdgcn_mfma_f32_16x16x32_bf16(vf1, pf1, pv[db], 0, 0, 0);
      }

      if (t + 1 < ntiles) AWRITE((t + 1) & 1);
      __syncthreads();
    }

    float inv = 1.0f / l_run;
#pragma unroll
    for (int db = 0; db < 8; ++db) {
      ushort4 o;
      o.x = f2bf(pv[db][0] * inv);
      o.y = f2bf(pv[db][1] * inv);
      o.z = f2bf(pv[db][2] * inv);
      o.w = f2bf(pv[db][3] * inv);
      *(ushort4*)(ctx + (size_t)qrow * HID + h * HDD + db * 16 + 4 * g) = o;
    }
    __syncthreads();
  }
#undef ALOAD
#undef AWRITE
}

// ---------------- launcher -------------------------------------------------
extern "C" void kernel_launch(void* const* d_in, const int* in_sizes, int n_in,
                              void* d_out, int out_size, void* d_ws, size_t ws_size,
                              hipStream_t stream) {
  const float* hidden = (const float*)d_in[0];
  const int* pid = (const int*)d_in[1];
  const float* wqkv = (const float*)d_in[3];
  const float* bqkv = (const float*)d_in[4];
  const float* wdense = (const float*)d_in[5];
  const float* bdense = (const float*)d_in[6];
  float* out = (float*)d_out;

  char* ws = (char*)d_ws;
  u16* W1 = (u16*)ws;                        // [12288][4096] bf16
  u16* X = (u16*)(ws + 134217728);           // [2048][4096] bf16
  u16* mixed = (u16*)(ws + 150994944);       // [2048][12288] bf16
  u16* ctx = (u16*)(ws + 201326592);         // [2048][4096] bf16
  float* cos_t = (float*)(ws + 218103808);
  float* sin_t = (float*)(ws + 218365952);

  cvt3_kernel<<<dim3(2048), dim3(256), 0, stream>>>(
      wqkv, W1, N_QKV * KDIM / 4, hidden, X, S_LEN * HID / 4, cos_t, sin_t);

  gemmQ<<<dim3(256), dim3(512), 0, stream>>>(X, W1, bqkv, mixed);

  ropek_kernel<<<dim3(4096), dim3(256), 0, stream>>>(mixed, pid, cos_t, sin_t);

  // attention: R15 structure, head-major grid for per-XCD K/V L2 locality
  attn_kernel<<<dim3(256), dim3(512), 0, stream>>>(mixed, pid, cos_t, sin_t, ctx);

  gemmD<<<dim3(256), dim3(512), 0, stream>>>(ctx, wdense, bdense, out);
}